// Round 2
// baseline (57.600 us; speedup 1.0000x reference)
//
#include <hip/hip_runtime.h>
#include <math.h>

#define B_TOTAL 4194304
#define NJ 6
#define BLK 256
#define IN_PER_BLK (BLK * NJ)    // 1536 floats
#define OUT_PER_BLK (BLK * 7)    // 1792 floats

__global__ void __launch_bounds__(BLK)
fk_kernel(const float* __restrict__ ja,
          const float* __restrict__ a,
          const float* __restrict__ d,
          const float* __restrict__ alpha,
          float* __restrict__ out) {
    __shared__ __align__(16) float s_in[IN_PER_BLK];
    __shared__ __align__(16) float s_out[OUT_PER_BLK];
    __shared__ __align__(16) float s_par[NJ * 4];   // [ca, sa, a, d] per joint

    const int t = threadIdx.x;
    const size_t blk = blockIdx.x;

    // ---- coalesced input stage: 1536 floats as 768 float2 (3 per thread) ----
    const float2* g2 = reinterpret_cast<const float2*>(ja + blk * IN_PER_BLK);
    float2* l2 = reinterpret_cast<float2*>(s_in);
#pragma unroll
    for (int k = 0; k < 3; ++k) l2[t + BLK * k] = g2[t + BLK * k];

    if (t < NJ) {
        float al = alpha[t];
        s_par[t * 4 + 0] = cosf(al);   // precise: feeds every row
        s_par[t * 4 + 1] = sinf(al);
        s_par[t * 4 + 2] = a[t];
        s_par[t * 4 + 3] = d[t];
    }
    __syncthreads();

    // ---- per-row compute ----
    const float2* row = reinterpret_cast<const float2*>(s_in + t * NJ);
    float2 j01 = row[0];
    float2 j23 = row[1];
    float2 j45 = row[2];
    float th[6] = { j01.x, j01.y, j23.x, j23.y, j45.x, j45.y };

    const float4* par4 = reinterpret_cast<const float4*>(s_par);

    float m00 = 1.f, m01 = 0.f, m02 = 0.f, m03 = 0.f;
    float m10 = 0.f, m11 = 1.f, m12 = 0.f, m13 = 0.f;
    float m20 = 0.f, m21 = 0.f, m22 = 1.f, m23 = 0.f;

#pragma unroll
    for (int i = 0; i < NJ; ++i) {
        float st, ct;
        __sincosf(th[i], &st, &ct);
        float4 p = par4[i];           // broadcast LDS read (conflict-free)
        float ca = p.x, sa = p.y, ai = p.z, di = p.w;

        float t01 = -st * ca, t11 = ct * ca;
        float t02 =  st * sa, t12 = -ct * sa;
        float t03 =  ai * ct, t13 =  ai * st;

        float n00 = m00 * ct  + m01 * st;
        float n01 = m00 * t01 + m01 * t11 + m02 * sa;
        float n02 = m00 * t02 + m01 * t12 + m02 * ca;
        float n03 = m00 * t03 + m01 * t13 + m02 * di + m03;

        float n10 = m10 * ct  + m11 * st;
        float n11 = m10 * t01 + m11 * t11 + m12 * sa;
        float n12 = m10 * t02 + m11 * t12 + m12 * ca;
        float n13 = m10 * t03 + m11 * t13 + m12 * di + m13;

        float n20 = m20 * ct  + m21 * st;
        float n21 = m20 * t01 + m21 * t11 + m22 * sa;
        float n22 = m20 * t02 + m21 * t12 + m22 * ca;
        float n23 = m20 * t03 + m21 * t13 + m22 * di + m23;

        m00 = n00; m01 = n01; m02 = n02; m03 = n03;
        m10 = n10; m11 = n11; m12 = n12; m13 = n13;
        m20 = n20; m21 = n21; m22 = n22; m23 = n23;
    }

    float trace = m00 + m11 + m22;
    float qw, qx, qy, qz;
    if (trace > 0.f) {
        float s = sqrtf(trace + 1.f) * 2.f;
        qw = 0.25f * s;
        qx = (m21 - m12) / s;
        qy = (m02 - m20) / s;
        qz = (m10 - m01) / s;
    } else {
        qw = 0.f; qx = 0.f; qy = 0.f; qz = 0.f;
    }

    // ---- stage output: stride-7 (coprime with 32 banks -> conflict-free) ----
    float* o = s_out + t * 7;
    o[0] = m03; o[1] = m13; o[2] = m23;
    o[3] = qw;  o[4] = qx;  o[5] = qy;  o[6] = qz;
    __syncthreads();

    // ---- coalesced output store: 1792 floats = 768 float2 + 256 floats ----
    float* og = out + blk * OUT_PER_BLK;
    float2* og2 = reinterpret_cast<float2*>(og);
    const float2* ol2 = reinterpret_cast<const float2*>(s_out);
#pragma unroll
    for (int k = 0; k < 3; ++k) og2[t + BLK * k] = ol2[t + BLK * k];
    og[1536 + t] = s_out[1536 + t];
}

extern "C" void kernel_launch(void* const* d_in, const int* in_sizes, int n_in,
                              void* d_out, int out_size, void* d_ws, size_t ws_size,
                              hipStream_t stream) {
    const float* ja    = (const float*)d_in[0];
    const float* a     = (const float*)d_in[1];
    const float* d     = (const float*)d_in[2];
    const float* alpha = (const float*)d_in[3];
    float* out = (float*)d_out;

    int blocks = B_TOTAL / BLK;   // 16384
    fk_kernel<<<blocks, BLK, 0, stream>>>(ja, a, d, alpha, out);
}

// Round 3
// 44.392 us; speedup vs baseline: 1.2975x; 1.2975x over previous
//
#include <hip/hip_runtime.h>
#include <math.h>

#define B_TOTAL 4194304
#define NJ 6
#define BLK 256
#define ROWS_PER_BLK (BLK * 2)            // 512 rows/block, 2 per thread
#define IN_F (ROWS_PER_BLK * NJ)          // 3072 floats
#define OUT_F (ROWS_PER_BLK * 7)          // 3584 floats

__global__ void __launch_bounds__(BLK)
fk_kernel(const float* __restrict__ ja,
          const float* __restrict__ a,
          const float* __restrict__ d,
          const float* __restrict__ alpha,
          float* __restrict__ out) {
    // one buffer, reused for input staging then output staging (union)
    __shared__ __align__(16) float s_buf[OUT_F];
    __shared__ __align__(16) float s_par[NJ * 4];   // [ca, sa, a, d] per joint

    const int t = threadIdx.x;
    const size_t blk = blockIdx.x;

    // ---- coalesced input stage: 3072 floats = 1536 float2, 6 per thread ----
    const float2* g2 = reinterpret_cast<const float2*>(ja + blk * IN_F);
    float2* l2 = reinterpret_cast<float2*>(s_buf);
#pragma unroll
    for (int k = 0; k < 6; ++k) l2[t + BLK * k] = g2[t + BLK * k];

    if (t < NJ) {
        float al = alpha[t];
        s_par[t * 4 + 0] = cosf(al);   // precise: feeds every row
        s_par[t * 4 + 1] = sinf(al);
        s_par[t * 4 + 2] = a[t];
        s_par[t * 4 + 3] = d[t];
    }
    __syncthreads();

    // ---- read my two consecutive rows into registers ----
    float th0[NJ], th1[NJ];
    {
        const float2* r = reinterpret_cast<const float2*>(s_buf + t * 12);
#pragma unroll
        for (int k = 0; k < 3; ++k) {
            float2 v0 = r[k];
            th0[2 * k] = v0.x; th0[2 * k + 1] = v0.y;
            float2 v1 = r[3 + k];
            th1[2 * k] = v1.x; th1[2 * k + 1] = v1.y;
        }
    }
    __syncthreads();   // all reads of s_buf done; safe to reuse for output

    const float4* par4 = reinterpret_cast<const float4*>(s_par);

    // two independent 3x4 affine states (ILP)
    float A00 = 1.f, A01 = 0.f, A02 = 0.f, A03 = 0.f;
    float A10 = 0.f, A11 = 1.f, A12 = 0.f, A13 = 0.f;
    float A20 = 0.f, A21 = 0.f, A22 = 1.f, A23 = 0.f;
    float B00 = 1.f, B01 = 0.f, B02 = 0.f, B03 = 0.f;
    float B10 = 0.f, B11 = 1.f, B12 = 0.f, B13 = 0.f;
    float B20 = 0.f, B21 = 0.f, B22 = 1.f, B23 = 0.f;

#pragma unroll
    for (int i = 0; i < NJ; ++i) {
        float sA, cA, sB, cB;
        __sincosf(th0[i], &sA, &cA);
        __sincosf(th1[i], &sB, &cB);
        float4 p = par4[i];            // broadcast LDS read
        float ca = p.x, sa = p.y, ai = p.z, di = p.w;

        // row update: u = m0*ct + m1*st ; v = m1*ct - m0*st
        // n0 = u ; n1 = ca*v + sa*m2 ; n2 = ca*m2 - sa*v ; n3 = ai*u + di*m2 + m3
#define ROWUP(m0, m1, m2, m3, ct, st)                    \
        {                                                \
            float u = m0 * ct + m1 * st;                 \
            float v = m1 * ct - m0 * st;                 \
            float w = ca * m2 - sa * v;                  \
            float x_ = ai * u + (di * m2 + m3);          \
            m1 = ca * v + sa * m2;                       \
            m0 = u; m2 = w; m3 = x_;                     \
        }
        ROWUP(A00, A01, A02, A03, cA, sA)
        ROWUP(B00, B01, B02, B03, cB, sB)
        ROWUP(A10, A11, A12, A13, cA, sA)
        ROWUP(B10, B11, B12, B13, cB, sB)
        ROWUP(A20, A21, A22, A23, cA, sA)
        ROWUP(B20, B21, B22, B23, cB, sB)
#undef ROWUP
    }

    // ---- quaternion (reference semantics), rsq instead of sqrt+div ----
    float o0[7], o1[7];
#define QUAT(M, O)                                                     \
    {                                                                  \
        float tr = M##00 + M##11 + M##22;                              \
        float qw, qx, qy, qz;                                          \
        if (tr > 0.f) {                                                \
            float r = __builtin_amdgcn_rsqf(tr + 1.f);                 \
            float h = 0.5f * r;                                        \
            qw = (tr + 1.f) * h;                                       \
            qx = (M##21 - M##12) * h;                                  \
            qy = (M##02 - M##20) * h;                                  \
            qz = (M##10 - M##01) * h;                                  \
        } else { qw = 0.f; qx = 0.f; qy = 0.f; qz = 0.f; }             \
        O[0] = M##03; O[1] = M##13; O[2] = M##23;                      \
        O[3] = qw; O[4] = qx; O[5] = qy; O[6] = qz;                    \
    }
    QUAT(A, o0)
    QUAT(B, o1)
#undef QUAT

    // ---- stage outputs (rows 2t, 2t+1) then coalesced store ----
    {
        float2* w = reinterpret_cast<float2*>(s_buf + t * 14);
        w[0] = make_float2(o0[0], o0[1]);
        w[1] = make_float2(o0[2], o0[3]);
        w[2] = make_float2(o0[4], o0[5]);
        w[3] = make_float2(o0[6], o1[0]);
        w[4] = make_float2(o1[1], o1[2]);
        w[5] = make_float2(o1[3], o1[4]);
        w[6] = make_float2(o1[5], o1[6]);
    }
    __syncthreads();

    float2* og2 = reinterpret_cast<float2*>(out + blk * OUT_F);
    const float2* ol2 = reinterpret_cast<const float2*>(s_buf);
#pragma unroll
    for (int k = 0; k < 7; ++k) og2[t + BLK * k] = ol2[t + BLK * k];
}

extern "C" void kernel_launch(void* const* d_in, const int* in_sizes, int n_in,
                              void* d_out, int out_size, void* d_ws, size_t ws_size,
                              hipStream_t stream) {
    const float* ja    = (const float*)d_in[0];
    const float* a     = (const float*)d_in[1];
    const float* d     = (const float*)d_in[2];
    const float* alpha = (const float*)d_in[3];
    float* out = (float*)d_out;

    int blocks = B_TOTAL / ROWS_PER_BLK;   // 8192
    fk_kernel<<<blocks, BLK, 0, stream>>>(ja, a, d, alpha, out);
}

// Round 4
// 41.925 us; speedup vs baseline: 1.3739x; 1.0589x over previous
//
#include <hip/hip_runtime.h>
#include <math.h>

#define B_TOTAL 4194304
#define NJ 6
#define BLK 256
#define RPT 4                          // rows (chains) per thread
#define ROWS (BLK * RPT)               // 1024 rows per block
#define IN_F (ROWS * NJ)               // 6144 floats = 24 KB
#define OUT_F (ROWS * 7)               // 7168 floats = 28 KB

__global__ void __launch_bounds__(BLK)
fk_kernel(const float* __restrict__ ja,
          const float* __restrict__ a,
          const float* __restrict__ d,
          const float* __restrict__ alpha,
          float* __restrict__ out) {
    // single buffer: input staging, then (after all reads) output staging
    __shared__ __align__(16) float s_buf[OUT_F];
    __shared__ __align__(16) float s_par[NJ * 4];   // [ca, sa, a, d]

    const int t = threadIdx.x;
    const size_t blk = blockIdx.x;

    // ---- coalesced input stage: 6144 floats = 1536 float4, 6 per thread ----
    {
        const float4* g4 = reinterpret_cast<const float4*>(ja + blk * IN_F);
        float4* l4 = reinterpret_cast<float4*>(s_buf);
#pragma unroll
        for (int k = 0; k < IN_F / 4 / BLK; ++k)   // 6
            l4[t + BLK * k] = g4[t + BLK * k];
    }
    if (t < NJ) {
        float al = alpha[t];
        s_par[t * 4 + 0] = cosf(al);
        s_par[t * 4 + 1] = sinf(al);
        s_par[t * 4 + 2] = a[t];
        s_par[t * 4 + 3] = d[t];
    }
    __syncthreads();

    // ---- read 4 strided rows (t, t+256, t+512, t+768) into registers ----
    // row base ℓ*6 floats = ℓ*3 float2; stride 3 pairs, gcd(3,16)=1 → conflict-free
    float th[RPT][NJ];
#pragma unroll
    for (int c = 0; c < RPT; ++c) {
        const float2* r = reinterpret_cast<const float2*>(s_buf + (t + BLK * c) * NJ);
#pragma unroll
        for (int k = 0; k < 3; ++k) {
            float2 v = r[k];
            th[c][2 * k] = v.x;
            th[c][2 * k + 1] = v.y;
        }
    }
    __syncthreads();   // all reads done; s_buf reusable for output

    const float4* par4 = reinterpret_cast<const float4*>(s_par);

    // ---- 4 independent 3x4 affine chains (all indices static after unroll) ----
    float M[RPT][12];
#pragma unroll
    for (int c = 0; c < RPT; ++c) {
#pragma unroll
        for (int k = 0; k < 12; ++k) M[c][k] = 0.f;
        M[c][0] = 1.f; M[c][5] = 1.f; M[c][10] = 1.f;
    }

#pragma unroll
    for (int i = 0; i < NJ; ++i) {
        float4 p = par4[i];            // broadcast LDS read
        float ca = p.x, sa = p.y, ai = p.z, di = p.w;

        float sn[RPT], cs[RPT];
#pragma unroll
        for (int c = 0; c < RPT; ++c) __sincosf(th[c][i], &sn[c], &cs[c]);

#pragma unroll
        for (int c = 0; c < RPT; ++c) {
            float ct = cs[c], st = sn[c];
#pragma unroll
            for (int rrow = 0; rrow < 3; ++rrow) {
                float m0 = M[c][rrow * 4 + 0];
                float m1 = M[c][rrow * 4 + 1];
                float m2 = M[c][rrow * 4 + 2];
                float m3 = M[c][rrow * 4 + 3];
                float u = m0 * ct + m1 * st;
                float v = m1 * ct - m0 * st;
                M[c][rrow * 4 + 0] = u;
                M[c][rrow * 4 + 1] = ca * v + sa * m2;
                M[c][rrow * 4 + 2] = ca * m2 - sa * v;
                M[c][rrow * 4 + 3] = ai * u + (di * m2 + m3);
            }
        }
    }

    // ---- quaternion (branchless, reference semantics) + stage to LDS ----
    // row ℓ at s_buf[ℓ*7]; scalar writes stride 7 (odd) → conflict-free
#pragma unroll
    for (int c = 0; c < RPT; ++c) {
        float m00 = M[c][0], m01 = M[c][1], m02 = M[c][2],  m03 = M[c][3];
        float m10 = M[c][4], m11 = M[c][5], m12 = M[c][6],  m13 = M[c][7];
        float m20 = M[c][8], m21 = M[c][9], m22 = M[c][10], m23 = M[c][11];
        float tr = m00 + m11 + m22;
        bool ok = tr > 0.f;
        float tr1 = tr + 1.f;
        float r = __builtin_amdgcn_rsqf(ok ? tr1 : 1.f);
        float h = 0.5f * r;
        float qw = ok ? tr1 * h : 0.f;
        float qx = ok ? (m21 - m12) * h : 0.f;
        float qy = ok ? (m02 - m20) * h : 0.f;
        float qz = ok ? (m10 - m01) * h : 0.f;

        float* o = s_buf + (t + BLK * c) * 7;
        o[0] = m03; o[1] = m13; o[2] = m23;
        o[3] = qw;  o[4] = qx;  o[5] = qy;  o[6] = qz;
    }
    __syncthreads();

    // ---- coalesced output store: 7168 floats = 1792 float4, 7 per thread ----
    {
        float4* og4 = reinterpret_cast<float4*>(out + blk * OUT_F);
        const float4* ol4 = reinterpret_cast<const float4*>(s_buf);
#pragma unroll
        for (int k = 0; k < OUT_F / 4 / BLK; ++k)   // 7
            og4[t + BLK * k] = ol4[t + BLK * k];
    }
}

extern "C" void kernel_launch(void* const* d_in, const int* in_sizes, int n_in,
                              void* d_out, int out_size, void* d_ws, size_t ws_size,
                              hipStream_t stream) {
    const float* ja    = (const float*)d_in[0];
    const float* a     = (const float*)d_in[1];
    const float* d     = (const float*)d_in[2];
    const float* alpha = (const float*)d_in[3];
    float* out = (float*)d_out;

    int blocks = B_TOTAL / ROWS;   // 4096
    fk_kernel<<<blocks, BLK, 0, stream>>>(ja, a, d, alpha, out);
}

// Round 8
// 38.275 us; speedup vs baseline: 1.5049x; 1.0954x over previous
//
#include <hip/hip_runtime.h>
#include <math.h>

#define B_TOTAL 4194304
#define NJ 6
#define BLK 256
#define RPT 4                          // rows (chains) per thread
#define ROWS (BLK * RPT)               // 1024 rows per block
#define IN_F (ROWS * NJ)               // 6144 floats = 24 KB
#define OUT_F (ROWS * 7)               // 7168 floats = 28 KB

// f32-exact DH constants (identical decimal -> identical f32 as reference):
#define A1c (-0.425f)
#define A2c (-0.3922f)
#define D0c (0.1625f)
#define D3c (0.1333f)
#define D4c (0.0997f)
#define D5c (0.0996f)
// alpha = [1.5708, 0, 0, 1.5708, -1.5708, 0]:
//   sin(+-1.5708f) = +-1.0f EXACT in f32; cos(1.5708f) = eps ~ -3.67e-6 (inexact,
//   computed on device from alpha[0] with precise cosf; cos is even -> serves J4 too).

__global__ void __launch_bounds__(BLK)
fk_kernel(const float* __restrict__ ja, const float* __restrict__ alpha,
          float* __restrict__ out) {
    // single LDS buffer: input staging, then (after all reads) output staging
    __shared__ __align__(16) float s_buf[OUT_F];
    __shared__ float s_eps;

    const int t = threadIdx.x;
    const size_t blk = blockIdx.x;

    // ---- coalesced input stage: 6144 floats = 1536 float4 ----
    {
        const float4* g4 = reinterpret_cast<const float4*>(ja + blk * IN_F);
        float4* l4 = reinterpret_cast<float4*>(s_buf);
#pragma unroll
        for (int k = 0; k < IN_F / 4 / BLK; ++k)   // 6
            l4[t + BLK * k] = g4[t + BLK * k];
    }
    if (t == 0) s_eps = cosf(alpha[0]);
    __syncthreads();

    // ---- read 4 strided rows (t, t+256, t+512, t+768) ----
    float th[RPT][NJ];
#pragma unroll
    for (int c = 0; c < RPT; ++c) {
        const float2* r = reinterpret_cast<const float2*>(s_buf + (t + BLK * c) * NJ);
#pragma unroll
        for (int k = 0; k < 3; ++k) {
            float2 v = r[k];
            th[c][2 * k] = v.x;
            th[c][2 * k + 1] = v.y;
        }
    }
    const float eps = s_eps;
    __syncthreads();   // s_buf reusable for output

    float o[RPT][7];
#pragma unroll
    for (int c = 0; c < RPT; ++c) {
        float sn[NJ], cs[NJ];
#pragma unroll
        for (int i = 0; i < NJ; ++i) __sincosf(th[c][i], &sn[i], &cs[i]);

        // ---- chain-faithful specialized FK (mirrors R4's ROWUP dataflow) ----
        // J0 folded: M = I*T0 exactly (ca=eps, sa=1, a=0, d=D0c)
        float m00 = cs[0], m01 = -sn[0] * eps, m02 = sn[0],  m03 = 0.f;
        float m10 = sn[0], m11 =  cs[0] * eps, m12 = -cs[0], m13 = 0.f;
        float m20 = 0.f,   m21 = 1.f,          m22 = eps,    m23 = D0c;

        // J1/J2: ca=1, sa=0, d=0 -> pure z-rotation + a*u translate (exact folds)
#define ZROT_A(CT, ST, AA)                                          \
        { float u, v;                                               \
          u = m00 * CT + m01 * ST; v = m01 * CT - m00 * ST;         \
          m03 = AA * u + m03; m00 = u; m01 = v;                     \
          u = m10 * CT + m11 * ST; v = m11 * CT - m10 * ST;         \
          m13 = AA * u + m13; m10 = u; m11 = v;                     \
          u = m20 * CT + m21 * ST; v = m21 * CT - m20 * ST;         \
          m23 = AA * u + m23; m20 = u; m21 = v; }
        ZROT_A(cs[1], sn[1], A1c)
        ZROT_A(cs[2], sn[2], A2c)
#undef ZROT_A

        // J3: ca=eps, sa=+1, a=0, d=D3c
        { float u, v;
          u = m00 * cs[3] + m01 * sn[3]; v = m01 * cs[3] - m00 * sn[3];
          m03 = D3c * m02 + m03; m00 = u; m01 = eps * v + m02; m02 = eps * m02 - v;
          u = m10 * cs[3] + m11 * sn[3]; v = m11 * cs[3] - m10 * sn[3];
          m13 = D3c * m12 + m13; m10 = u; m11 = eps * v + m12; m12 = eps * m12 - v;
          u = m20 * cs[3] + m21 * sn[3]; v = m21 * cs[3] - m20 * sn[3];
          m23 = D3c * m22 + m23; m20 = u; m21 = eps * v + m22; m22 = eps * m22 - v; }

        // J4: ca=eps, sa=-1, a=0, d=D4c
        { float u, v;
          u = m00 * cs[4] + m01 * sn[4]; v = m01 * cs[4] - m00 * sn[4];
          m03 = D4c * m02 + m03; m00 = u; m01 = eps * v - m02; m02 = eps * m02 + v;
          u = m10 * cs[4] + m11 * sn[4]; v = m11 * cs[4] - m10 * sn[4];
          m13 = D4c * m12 + m13; m10 = u; m11 = eps * v - m12; m12 = eps * m12 + v;
          u = m20 * cs[4] + m21 * sn[4]; v = m21 * cs[4] - m20 * sn[4];
          m23 = D4c * m22 + m23; m20 = u; m21 = eps * v - m22; m22 = eps * m22 + v; }

        // J5: ca=1, sa=0, a=0, d=D5c
        { float u, v;
          u = m00 * cs[5] + m01 * sn[5]; v = m01 * cs[5] - m00 * sn[5];
          m03 = D5c * m02 + m03; m00 = u; m01 = v;
          u = m10 * cs[5] + m11 * sn[5]; v = m11 * cs[5] - m10 * sn[5];
          m13 = D5c * m12 + m13; m10 = u; m11 = v;
          u = m20 * cs[5] + m21 * sn[5]; v = m21 * cs[5] - m20 * sn[5];
          m23 = D5c * m22 + m23; m20 = u; m21 = v; }

        // quaternion (reference semantics: trace>0 branch else zeros), branchless
        float tr = m00 + m11 + m22;
        bool ok = tr > 0.f;
        float tr1 = tr + 1.f;
        float rr = __builtin_amdgcn_rsqf(ok ? tr1 : 1.f);
        float h = 0.5f * rr;
        o[c][0] = m03;
        o[c][1] = m13;
        o[c][2] = m23;
        o[c][3] = ok ? tr1 * h : 0.f;
        o[c][4] = ok ? (m21 - m12) * h : 0.f;
        o[c][5] = ok ? (m02 - m20) * h : 0.f;
        o[c][6] = ok ? (m10 - m01) * h : 0.f;
    }

    // ---- stage outputs (stride 7 = odd -> conflict-free) ----
#pragma unroll
    for (int c = 0; c < RPT; ++c) {
        float* p = s_buf + (t + BLK * c) * 7;
#pragma unroll
        for (int k = 0; k < 7; ++k) p[k] = o[c][k];
    }
    __syncthreads();

    // ---- coalesced output store: 7168 floats = 1792 float4 ----
    {
        float4* og4 = reinterpret_cast<float4*>(out + blk * OUT_F);
        const float4* ol4 = reinterpret_cast<const float4*>(s_buf);
#pragma unroll
        for (int k = 0; k < OUT_F / 4 / BLK; ++k)   // 7
            og4[t + BLK * k] = ol4[t + BLK * k];
    }
}

extern "C" void kernel_launch(void* const* d_in, const int* in_sizes, int n_in,
                              void* d_out, int out_size, void* d_ws, size_t ws_size,
                              hipStream_t stream) {
    const float* ja    = (const float*)d_in[0];
    const float* alpha = (const float*)d_in[3];
    float* out = (float*)d_out;
    int blocks = B_TOTAL / ROWS;   // 4096
    fk_kernel<<<blocks, BLK, 0, stream>>>(ja, alpha, out);
}